// Round 7
// baseline (3382.256 us; speedup 1.0000x reference)
//
#include <hip/hip_runtime.h>

typedef __attribute__((ext_vector_type(8))) short bf16x8;
typedef __attribute__((ext_vector_type(4))) float f32x4;

#define AF 0.8f
#define BF (1.0f - 0.8f)
#define EPS 1e-5f

__device__ __forceinline__ ushort f2bf(float f) {
    union { float f; unsigned u; } v; v.f = f;
    unsigned u = v.u;
    return (ushort)((u + 0x7fffu + ((u >> 16) & 1u)) >> 16);
}

// ---------------- degree / edge value ----------------
__global__ void deg_k(const int* __restrict__ rows, const float* __restrict__ w,
                      float* __restrict__ deg, int E) {
    int e = blockIdx.x * 256 + threadIdx.x;
    if (e < E) atomicAdd(&deg[rows[e]], w[e]);
}

__global__ void dinv_k(const float* __restrict__ deg, float* __restrict__ dinv, int n) {
    int i = blockIdx.x * 256 + threadIdx.x;
    if (i < n) {
        float d = deg[i];
        d = d < 0.5f ? d + 1.0f : d;
        dinv[i] = rsqrtf(d);
    }
}

__global__ void edgeval_k(const int* __restrict__ rows, const int* __restrict__ cols,
                          const float* __restrict__ w, const float* __restrict__ dinv,
                          float* __restrict__ val, int E) {
    int e = blockIdx.x * 256 + threadIdx.x;
    if (e < E) val[e] = dinv[rows[e]] * w[e] * dinv[cols[e]];
}

// ---------------- GEMM: out[r][c] = sum_k X[r][k]*W[c][k] + bias[c] -------------
// bf16 MFMA 16x16x32. Block = 256 thr (4 waves), 64 rows x 128 cols per block.
__global__ __launch_bounds__(256) void gemm_xwt(const float* __restrict__ X,
                                                const float* __restrict__ W,
                                                const float* __restrict__ bias,
                                                float* __restrict__ out, int R) {
    __shared__ ushort Wl[128 * 136];  // padded +8 bf16 per row
    __shared__ ushort Xl[64 * 136];
    int t = threadIdx.x;
    int row0 = blockIdx.x * 64;

    // stage W (128x128 f32 -> bf16), 16 float4 per thread
    for (int i = 0; i < 16; i++) {
        int vid = t + i * 256;
        int idx = vid * 4;
        int r = idx >> 7, c = idx & 127;
        float4 v = reinterpret_cast<const float4*>(W)[vid];
        ushort4 b;
        b.x = f2bf(v.x); b.y = f2bf(v.y); b.z = f2bf(v.z); b.w = f2bf(v.w);
        *reinterpret_cast<ushort4*>(&Wl[r * 136 + c]) = b;
    }
    // stage X tile (64x128), zero-fill beyond R
    for (int i = 0; i < 8; i++) {
        int vid = t + i * 256;
        int idx = vid * 4;
        int r = idx >> 7, c = idx & 127;
        int gr = row0 + r;
        float4 v = make_float4(0.f, 0.f, 0.f, 0.f);
        if (gr < R) v = reinterpret_cast<const float4*>(X)[(size_t)gr * 32 + (c >> 2)];
        ushort4 b;
        b.x = f2bf(v.x); b.y = f2bf(v.y); b.z = f2bf(v.z); b.w = f2bf(v.w);
        *reinterpret_cast<ushort4*>(&Xl[r * 136 + c]) = b;
    }
    __syncthreads();

    int w = t >> 6, l = t & 63;
    int lr = l & 15, lg = l >> 4;

    f32x4 acc[8] = {};
#pragma unroll
    for (int kk = 0; kk < 4; kk++) {
        bf16x8 a = *reinterpret_cast<const bf16x8*>(&Xl[(w * 16 + lr) * 136 + kk * 32 + lg * 8]);
#pragma unroll
        for (int j = 0; j < 8; j++) {
            bf16x8 b = *reinterpret_cast<const bf16x8*>(&Wl[(j * 16 + lr) * 136 + kk * 32 + lg * 8]);
            acc[j] = __builtin_amdgcn_mfma_f32_16x16x32_bf16(a, b, acc[j], 0, 0, 0);
        }
    }
    // C/D layout: col = lane&15, row = 4*(lane>>4)+reg  [m89-verified]
#pragma unroll
    for (int j = 0; j < 8; j++) {
        int c = j * 16 + lr;
        float bi = bias[c];
#pragma unroll
        for (int i = 0; i < 4; i++) {
            int r = row0 + w * 16 + lg * 4 + i;
            if (r < R) out[(size_t)r * 128 + c] = acc[j][i] + bi;
        }
    }
}

// ---------------- SpMM scatter: out[row] += val * x[col] ----------------
// 32 lanes per edge, float4 per lane.
__global__ void spmm_scatter(const int* __restrict__ rows, const int* __restrict__ cols,
                             const float* __restrict__ val, const float* __restrict__ x,
                             float* __restrict__ out, int E) {
    int gid = blockIdx.x * 256 + threadIdx.x;
    int e = gid >> 5, lane = gid & 31;
    if (e >= E) return;
    int r = rows[e], c = cols[e];
    float v = val[e];
    float4 xv = reinterpret_cast<const float4*>(x)[(size_t)c * 32 + lane];
    float* o = out + (size_t)r * 128 + lane * 4;
    atomicAdd(o + 0, v * xv.x);
    atomicAdd(o + 1, v * xv.y);
    atomicAdd(o + 2, v * xv.z);
    atomicAdd(o + 3, v * xv.w);
}

// ---------------- column stats: sums[0:128]=sum, sums[128:256]=sumsq ----------
__global__ void colstats(const float* __restrict__ x, float* __restrict__ sums, int R) {
    int t = threadIdx.x;
    int g = t & 31, rb = t >> 5;  // col group (4 cols), row offset 0..7
    int r0 = blockIdx.x * 256;
    int rend = min(r0 + 256, R);
    float4 s = make_float4(0.f, 0.f, 0.f, 0.f);
    float4 q = make_float4(0.f, 0.f, 0.f, 0.f);
    for (int r = r0 + rb; r < rend; r += 8) {
        float4 v = reinterpret_cast<const float4*>(x)[(size_t)r * 32 + g];
        s.x += v.x; s.y += v.y; s.z += v.z; s.w += v.w;
        q.x += v.x * v.x; q.y += v.y * v.y; q.z += v.z * v.z; q.w += v.w * v.w;
    }
    s.x += __shfl_xor(s.x, 32); s.y += __shfl_xor(s.y, 32);
    s.z += __shfl_xor(s.z, 32); s.w += __shfl_xor(s.w, 32);
    q.x += __shfl_xor(q.x, 32); q.y += __shfl_xor(q.y, 32);
    q.z += __shfl_xor(q.z, 32); q.w += __shfl_xor(q.w, 32);
    if ((t & 32) == 0) {
        int c = g * 4;
        atomicAdd(&sums[c + 0], s.x); atomicAdd(&sums[c + 1], s.y);
        atomicAdd(&sums[c + 2], s.z); atomicAdd(&sums[c + 3], s.w);
        atomicAdd(&sums[128 + c + 0], q.x); atomicAdd(&sums[128 + c + 1], q.y);
        atomicAdd(&sums[128 + c + 2], q.z); atomicAdd(&sums[128 + c + 3], q.w);
    }
}

// stats[256+j]=scale, stats[384+j]=shift ; y = scale*x + shift
__global__ void finalize_stats(float* __restrict__ stats, const float* __restrict__ wgt,
                               const float* __restrict__ bias, const float* __restrict__ msc,
                               float R) {
    int j = threadIdx.x;
    float mean = stats[j] / R;
    float ex2 = stats[128 + j] / R;
    float ms = msc[j];
    float d = ms * mean;
    float var = ex2 - 2.0f * d * mean + d * d;
    float rstd = rsqrtf(var + EPS);
    float sc = wgt[j] * rstd;
    stats[256 + j] = sc;
    stats[384 + j] = bias[j] - sc * d;
}

// y = relu(scale*x+shift), in place
__global__ void apply_relu(float* __restrict__ x, const float* __restrict__ ss, int R) {
    __shared__ float lss[256];
    int t = threadIdx.x;
    lss[t] = ss[t];
    __syncthreads();
    int idx = blockIdx.x * 256 + t;
    if (idx >= R * 32) return;
    int c = (idx & 31) * 4;
    float4 v = reinterpret_cast<float4*>(x)[idx];
    v.x = fmaxf(lss[c + 0] * v.x + lss[128 + c + 0], 0.f);
    v.y = fmaxf(lss[c + 1] * v.y + lss[128 + c + 1], 0.f);
    v.z = fmaxf(lss[c + 2] * v.z + lss[128 + c + 2], 0.f);
    v.w = fmaxf(lss[c + 3] * v.w + lss[128 + c + 3], 0.f);
    reinterpret_cast<float4*>(x)[idx] = v;
}

// local_mixed = a*relu(lscale*lagg+lshift) + (1-a)*base_h[c2o]; scatter summ/cnt
__global__ void local_apply_mix(const float* __restrict__ lagg, const float* __restrict__ ss,
                                const float* __restrict__ base_h, const int* __restrict__ c2o,
                                float* __restrict__ out_local, float* __restrict__ summ,
                                float* __restrict__ cnt, int M) {
    __shared__ float lss[256];
    int t = threadIdx.x;
    lss[t] = ss[t];
    __syncthreads();
    int gid = blockIdx.x * 256 + t;
    int m = gid >> 5, lane = gid & 31;
    if (m >= M) return;
    int n = c2o[m];
    if (lane == 0) atomicAdd(&cnt[n], 1.0f);
    float4 lv = reinterpret_cast<const float4*>(lagg)[(size_t)m * 32 + lane];
    float4 bv = reinterpret_cast<const float4*>(base_h)[(size_t)n * 32 + lane];
    int c = lane * 4;
    float4 o;
    o.x = AF * fmaxf(lss[c + 0] * lv.x + lss[128 + c + 0], 0.f) + BF * bv.x;
    o.y = AF * fmaxf(lss[c + 1] * lv.y + lss[128 + c + 1], 0.f) + BF * bv.y;
    o.z = AF * fmaxf(lss[c + 2] * lv.z + lss[128 + c + 2], 0.f) + BF * bv.z;
    o.w = AF * fmaxf(lss[c + 3] * lv.w + lss[128 + c + 3], 0.f) + BF * bv.w;
    reinterpret_cast<float4*>(out_local)[(size_t)m * 32 + lane] = o;
    float* sp = summ + (size_t)n * 128 + c;
    atomicAdd(sp + 0, o.x); atomicAdd(sp + 1, o.y);
    atomicAdd(sp + 2, o.z); atomicAdd(sp + 3, o.w);
}

__global__ void base_mixed_k(const float* __restrict__ base_h, const float* __restrict__ summ,
                             const float* __restrict__ cnt, float* __restrict__ out, int N_) {
    int gid = blockIdx.x * 256 + threadIdx.x;
    int n = gid >> 5, lane = gid & 31;
    if (n >= N_) return;
    float rc = 1.0f / fmaxf(cnt[n], 1.0f);
    float4 bh = reinterpret_cast<const float4*>(base_h)[(size_t)n * 32 + lane];
    float4 sm = reinterpret_cast<const float4*>(summ)[(size_t)n * 32 + lane];
    float4 o;
    o.x = AF * bh.x + BF * sm.x * rc;
    o.y = AF * bh.y + BF * sm.y * rc;
    o.z = AF * bh.z + BF * sm.z * rc;
    o.w = AF * bh.w + BF * sm.w * rc;
    reinterpret_cast<float4*>(out)[(size_t)n * 32 + lane] = o;
}

extern "C" void kernel_launch(void* const* d_in, const int* in_sizes, int n_in,
                              void* d_out, int out_size, void* d_ws, size_t ws_size,
                              hipStream_t stream) {
    const float* base_x  = (const float*)d_in[0];
    const int*   bei     = (const int*)d_in[1];
    const float* bew     = (const float*)d_in[2];
    const float* local_x = (const float*)d_in[3];
    const int*   lai     = (const int*)d_in[4];
    const float* lav     = (const float*)d_in[5];
    const int*   c2o     = (const int*)d_in[6];
    const float* bW      = (const float*)d_in[7];
    const float* bb      = (const float*)d_in[8];
    const float* lW      = (const float*)d_in[9];
    const float* lb      = (const float*)d_in[10];
    const float* bgnw    = (const float*)d_in[11];
    const float* bgnb    = (const float*)d_in[12];
    const float* bgnms   = (const float*)d_in[13];
    const float* lgnw    = (const float*)d_in[14];
    const float* lgnb    = (const float*)d_in[15];
    const float* lgnms   = (const float*)d_in[16];

    const int N  = in_sizes[0] / 128;
    const int E  = in_sizes[2];
    const int M  = in_sizes[3] / 128;
    const int EL = in_sizes[5];

    float* ws = (float*)d_ws;
    size_t off = 0;
    float* deg   = ws + off; off += N;
    float* dinv  = ws + off; off += N;
    float* cnt   = ws + off; off += N;
    float* stats = ws + off; off += 512;
    float* val   = ws + off; off += E;
    float* bx    = ws + off; off += (size_t)N * 128;  // later reused as summ
    float* agg   = ws + off; off += (size_t)N * 128;  // becomes base_h in place
    float* lx    = ws + off; off += (size_t)M * 128;
    float* lagg  = ws + off; off += (size_t)M * 128;
    float* summ  = bx;

    const int* brow = bei;
    const int* bcol = bei + E;
    const int* lrow = lai;
    const int* lcol = lai + EL;

    // degree + GCN edge normalization
    hipMemsetAsync(deg, 0, (size_t)N * sizeof(float), stream);
    deg_k<<<(E + 255) / 256, 256, 0, stream>>>(brow, bew, deg, E);
    dinv_k<<<(N + 255) / 256, 256, 0, stream>>>(deg, dinv, N);
    edgeval_k<<<(E + 255) / 256, 256, 0, stream>>>(brow, bcol, bew, dinv, val, E);

    // base: GEMM -> spmm -> graphnorm+relu (in place)
    gemm_xwt<<<(N + 63) / 64, 256, 0, stream>>>(base_x, bW, bb, bx, N);
    hipMemsetAsync(agg, 0, (size_t)N * 128 * sizeof(float), stream);
    spmm_scatter<<<(E * 32 + 255) / 256, 256, 0, stream>>>(brow, bcol, val, bx, agg, E);
    hipMemsetAsync(stats, 0, 256 * sizeof(float), stream);
    colstats<<<(N + 255) / 256, 256, 0, stream>>>(agg, stats, N);
    finalize_stats<<<1, 128, 0, stream>>>(stats, bgnw, bgnb, bgnms, (float)N);
    apply_relu<<<(N * 32 + 255) / 256, 256, 0, stream>>>(agg, stats + 256, N);

    // local: GEMM -> spmm -> stats
    gemm_xwt<<<(M + 63) / 64, 256, 0, stream>>>(local_x, lW, lb, lx, M);
    hipMemsetAsync(lagg, 0, (size_t)M * 128 * sizeof(float), stream);
    spmm_scatter<<<(EL * 32 + 255) / 256, 256, 0, stream>>>(lrow, lcol, lav, lx, lagg, EL);
    hipMemsetAsync(stats, 0, 256 * sizeof(float), stream);
    colstats<<<(M + 255) / 256, 256, 0, stream>>>(lagg, stats, M);
    finalize_stats<<<1, 128, 0, stream>>>(stats, lgnw, lgnb, lgnms, (float)M);

    // mixing
    hipMemsetAsync(summ, 0, (size_t)N * 128 * sizeof(float), stream);
    hipMemsetAsync(cnt, 0, (size_t)N * sizeof(float), stream);
    float* out_base  = (float*)d_out;
    float* out_local = out_base + (size_t)N * 128;
    local_apply_mix<<<(M * 32 + 255) / 256, 256, 0, stream>>>(lagg, stats + 256, agg, c2o,
                                                              out_local, summ, cnt, M);
    base_mixed_k<<<(N * 32 + 255) / 256, 256, 0, stream>>>(agg, summ, cnt, out_base, N);
}

// Round 8
// 1092.975 us; speedup vs baseline: 3.0945x; 3.0945x over previous
//
#include <hip/hip_runtime.h>

typedef __attribute__((ext_vector_type(8))) short bf16x8;
typedef __attribute__((ext_vector_type(4))) float f32x4;

#define AF 0.8f
#define BF (1.0f - 0.8f)
#define EPS 1e-5f

__device__ __forceinline__ ushort f2bf(float f) {
    union { float f; unsigned u; } v; v.f = f;
    unsigned u = v.u;
    return (ushort)((u + 0x7fffu + ((u >> 16) & 1u)) >> 16);
}

// ---------------- degree (weighted) + histogram (count) ----------------
__global__ void deg_hist_k(const int* __restrict__ rows, const float* __restrict__ w,
                           float* __restrict__ deg, int* __restrict__ hist, int E) {
    int e = blockIdx.x * 256 + threadIdx.x;
    if (e < E) {
        int r = rows[e];
        atomicAdd(&deg[r], w[e]);
        atomicAdd(&hist[r], 1);
    }
}

__global__ void hist_k(const int* __restrict__ rows, int* __restrict__ hist, int E) {
    int e = blockIdx.x * 256 + threadIdx.x;
    if (e < E) atomicAdd(&hist[rows[e]], 1);
}

__global__ void dinv_k(const float* __restrict__ deg, float* __restrict__ dinv, int n) {
    int i = blockIdx.x * 256 + threadIdx.x;
    if (i < n) {
        float d = deg[i];
        d = d < 0.5f ? d + 1.0f : d;
        dinv[i] = rsqrtf(d);
    }
}

// ---------------- exclusive scan (2-level, Hillis-Steele) ----------------
__global__ void scan1_k(const int* __restrict__ in, int* __restrict__ out,
                        int* __restrict__ bsum, int n) {
    __shared__ int sm[1024];
    int t = threadIdx.x;
    int i = blockIdx.x * 1024 + t;
    int v = (i < n) ? in[i] : 0;
    sm[t] = v;
    __syncthreads();
    for (int off = 1; off < 1024; off <<= 1) {
        int add = (t >= off) ? sm[t - off] : 0;
        __syncthreads();
        sm[t] += add;
        __syncthreads();
    }
    if (i < n) out[i] = sm[t] - v;  // exclusive
    if (t == 1023) bsum[blockIdx.x] = sm[1023];
}

__global__ void scan2_k(const int* __restrict__ bsum, int* __restrict__ boff, int n) {
    __shared__ int sm[128];
    int t = threadIdx.x;
    int v = (t < n) ? bsum[t] : 0;
    sm[t] = v;
    __syncthreads();
    for (int off = 1; off < 128; off <<= 1) {
        int add = (t >= off) ? sm[t - off] : 0;
        __syncthreads();
        sm[t] += add;
        __syncthreads();
    }
    if (t < n) boff[t] = sm[t] - v;  // exclusive
}

__global__ void scan3_k(int* __restrict__ out, const int* __restrict__ boff, int n) {
    int i = blockIdx.x * 1024 + threadIdx.x;
    if (i < n) out[i] += boff[blockIdx.x];
}

// ---------------- permute edges into row-sorted (CSR) order ----------------
// base graph: fuse GCN edge normalization val = dinv[r]*w*dinv[c]
__global__ void perm_b_k(const int* __restrict__ rows, const int* __restrict__ cols,
                         const float* __restrict__ w, const float* __restrict__ dinv,
                         const int* __restrict__ rowptr, int* __restrict__ cursor,
                         int* __restrict__ colv, float* __restrict__ valv, int E) {
    int e = blockIdx.x * 256 + threadIdx.x;
    if (e >= E) return;
    int r = rows[e], c = cols[e];
    int pos = rowptr[r] + atomicAdd(&cursor[r], 1);
    colv[pos] = c;
    valv[pos] = dinv[r] * w[e] * dinv[c];
}

__global__ void perm_l_k(const int* __restrict__ rows, const int* __restrict__ cols,
                         const float* __restrict__ w,
                         const int* __restrict__ rowptr, int* __restrict__ cursor,
                         int* __restrict__ colv, float* __restrict__ valv, int E) {
    int e = blockIdx.x * 256 + threadIdx.x;
    if (e >= E) return;
    int r = rows[e];
    int pos = rowptr[r] + atomicAdd(&cursor[r], 1);
    colv[pos] = cols[e];
    valv[pos] = w[e];
}

// ---------------- CSR SpMM: one wave per row, no atomics ----------------
__global__ void spmm_csr(const int* __restrict__ rowptr, const int* __restrict__ colv,
                         const float* __restrict__ valv, const float* __restrict__ x,
                         float* __restrict__ out, int R, int Etot) {
    int wid = (blockIdx.x * 256 + threadIdx.x) >> 6;
    int lane = threadIdx.x & 63;
    if (wid >= R) return;
    int s = rowptr[wid];
    int epos_end = (wid == R - 1) ? Etot : rowptr[wid + 1];
    float2 acc = make_float2(0.f, 0.f);
    for (int i = s; i < epos_end; i++) {
        int c = colv[i];
        float v = valv[i];
        float2 xv = reinterpret_cast<const float2*>(x)[(size_t)c * 64 + lane];
        acc.x += v * xv.x;
        acc.y += v * xv.y;
    }
    reinterpret_cast<float2*>(out)[(size_t)wid * 64 + lane] = acc;
}

// ---------------- GEMM: out[r][c] = sum_k X[r][k]*W[c][k] + bias[c] -------------
__global__ __launch_bounds__(256) void gemm_xwt(const float* __restrict__ X,
                                                const float* __restrict__ W,
                                                const float* __restrict__ bias,
                                                float* __restrict__ out, int R) {
    __shared__ ushort Wl[128 * 136];
    __shared__ ushort Xl[64 * 136];
    int t = threadIdx.x;
    int row0 = blockIdx.x * 64;

    for (int i = 0; i < 16; i++) {
        int vid = t + i * 256;
        int idx = vid * 4;
        int r = idx >> 7, c = idx & 127;
        float4 v = reinterpret_cast<const float4*>(W)[vid];
        ushort4 b;
        b.x = f2bf(v.x); b.y = f2bf(v.y); b.z = f2bf(v.z); b.w = f2bf(v.w);
        *reinterpret_cast<ushort4*>(&Wl[r * 136 + c]) = b;
    }
    for (int i = 0; i < 8; i++) {
        int vid = t + i * 256;
        int idx = vid * 4;
        int r = idx >> 7, c = idx & 127;
        int gr = row0 + r;
        float4 v = make_float4(0.f, 0.f, 0.f, 0.f);
        if (gr < R) v = reinterpret_cast<const float4*>(X)[(size_t)gr * 32 + (c >> 2)];
        ushort4 b;
        b.x = f2bf(v.x); b.y = f2bf(v.y); b.z = f2bf(v.z); b.w = f2bf(v.w);
        *reinterpret_cast<ushort4*>(&Xl[r * 136 + c]) = b;
    }
    __syncthreads();

    int w = t >> 6, l = t & 63;
    int lr = l & 15, lg = l >> 4;

    f32x4 acc[8] = {};
#pragma unroll
    for (int kk = 0; kk < 4; kk++) {
        bf16x8 a = *reinterpret_cast<const bf16x8*>(&Xl[(w * 16 + lr) * 136 + kk * 32 + lg * 8]);
#pragma unroll
        for (int j = 0; j < 8; j++) {
            bf16x8 b = *reinterpret_cast<const bf16x8*>(&Wl[(j * 16 + lr) * 136 + kk * 32 + lg * 8]);
            acc[j] = __builtin_amdgcn_mfma_f32_16x16x32_bf16(a, b, acc[j], 0, 0, 0);
        }
    }
#pragma unroll
    for (int j = 0; j < 8; j++) {
        int c = j * 16 + lr;
        float bi = bias[c];
#pragma unroll
        for (int i = 0; i < 4; i++) {
            int r = row0 + w * 16 + lg * 4 + i;
            if (r < R) out[(size_t)r * 128 + c] = acc[j][i] + bi;
        }
    }
}

// ---------------- column stats ----------------
__global__ void colstats(const float* __restrict__ x, float* __restrict__ sums, int R) {
    int t = threadIdx.x;
    int g = t & 31, rb = t >> 5;
    int r0 = blockIdx.x * 256;
    int rend = min(r0 + 256, R);
    float4 s = make_float4(0.f, 0.f, 0.f, 0.f);
    float4 q = make_float4(0.f, 0.f, 0.f, 0.f);
    for (int r = r0 + rb; r < rend; r += 8) {
        float4 v = reinterpret_cast<const float4*>(x)[(size_t)r * 32 + g];
        s.x += v.x; s.y += v.y; s.z += v.z; s.w += v.w;
        q.x += v.x * v.x; q.y += v.y * v.y; q.z += v.z * v.z; q.w += v.w * v.w;
    }
    s.x += __shfl_xor(s.x, 32); s.y += __shfl_xor(s.y, 32);
    s.z += __shfl_xor(s.z, 32); s.w += __shfl_xor(s.w, 32);
    q.x += __shfl_xor(q.x, 32); q.y += __shfl_xor(q.y, 32);
    q.z += __shfl_xor(q.z, 32); q.w += __shfl_xor(q.w, 32);
    if ((t & 32) == 0) {
        int c = g * 4;
        atomicAdd(&sums[c + 0], s.x); atomicAdd(&sums[c + 1], s.y);
        atomicAdd(&sums[c + 2], s.z); atomicAdd(&sums[c + 3], s.w);
        atomicAdd(&sums[128 + c + 0], q.x); atomicAdd(&sums[128 + c + 1], q.y);
        atomicAdd(&sums[128 + c + 2], q.z); atomicAdd(&sums[128 + c + 3], q.w);
    }
}

__global__ void finalize_stats(float* __restrict__ stats, const float* __restrict__ wgt,
                               const float* __restrict__ bias, const float* __restrict__ msc,
                               float R) {
    int j = threadIdx.x;
    float mean = stats[j] / R;
    float ex2 = stats[128 + j] / R;
    float ms = msc[j];
    float d = ms * mean;
    float var = ex2 - 2.0f * d * mean + d * d;
    float rstd = rsqrtf(var + EPS);
    float sc = wgt[j] * rstd;
    stats[256 + j] = sc;
    stats[384 + j] = bias[j] - sc * d;
}

__global__ void apply_relu(float* __restrict__ x, const float* __restrict__ ss, int R) {
    __shared__ float lss[256];
    int t = threadIdx.x;
    lss[t] = ss[t];
    __syncthreads();
    int idx = blockIdx.x * 256 + t;
    if (idx >= R * 32) return;
    int c = (idx & 31) * 4;
    float4 v = reinterpret_cast<float4*>(x)[idx];
    v.x = fmaxf(lss[c + 0] * v.x + lss[128 + c + 0], 0.f);
    v.y = fmaxf(lss[c + 1] * v.y + lss[128 + c + 1], 0.f);
    v.z = fmaxf(lss[c + 2] * v.z + lss[128 + c + 2], 0.f);
    v.w = fmaxf(lss[c + 3] * v.w + lss[128 + c + 3], 0.f);
    reinterpret_cast<float4*>(x)[idx] = v;
}

// local_mixed = a*relu(lscale*lagg+lshift) + (1-a)*base_h[c2o]; scatter summ/cnt
__global__ void local_apply_mix(const float* __restrict__ lagg, const float* __restrict__ ss,
                                const float* __restrict__ base_h, const int* __restrict__ c2o,
                                float* __restrict__ out_local, float* __restrict__ summ,
                                float* __restrict__ cnt, int M) {
    __shared__ float lss[256];
    int t = threadIdx.x;
    lss[t] = ss[t];
    __syncthreads();
    int gid = blockIdx.x * 256 + t;
    int m = gid >> 5, lane = gid & 31;
    if (m >= M) return;
    int n = c2o[m];
    if (lane == 0) atomicAdd(&cnt[n], 1.0f);
    float4 lv = reinterpret_cast<const float4*>(lagg)[(size_t)m * 32 + lane];
    float4 bv = reinterpret_cast<const float4*>(base_h)[(size_t)n * 32 + lane];
    int c = lane * 4;
    float4 o;
    o.x = AF * fmaxf(lss[c + 0] * lv.x + lss[128 + c + 0], 0.f) + BF * bv.x;
    o.y = AF * fmaxf(lss[c + 1] * lv.y + lss[128 + c + 1], 0.f) + BF * bv.y;
    o.z = AF * fmaxf(lss[c + 2] * lv.z + lss[128 + c + 2], 0.f) + BF * bv.z;
    o.w = AF * fmaxf(lss[c + 3] * lv.w + lss[128 + c + 3], 0.f) + BF * bv.w;
    reinterpret_cast<float4*>(out_local)[(size_t)m * 32 + lane] = o;
    float* sp = summ + (size_t)n * 128 + c;
    atomicAdd(sp + 0, o.x); atomicAdd(sp + 1, o.y);
    atomicAdd(sp + 2, o.z); atomicAdd(sp + 3, o.w);
}

__global__ void base_mixed_k(const float* __restrict__ base_h, const float* __restrict__ summ,
                             const float* __restrict__ cnt, float* __restrict__ out, int N_) {
    int gid = blockIdx.x * 256 + threadIdx.x;
    int n = gid >> 5, lane = gid & 31;
    if (n >= N_) return;
    float rc = 1.0f / fmaxf(cnt[n], 1.0f);
    float4 bh = reinterpret_cast<const float4*>(base_h)[(size_t)n * 32 + lane];
    float4 sm = reinterpret_cast<const float4*>(summ)[(size_t)n * 32 + lane];
    float4 o;
    o.x = AF * bh.x + BF * sm.x * rc;
    o.y = AF * bh.y + BF * sm.y * rc;
    o.z = AF * bh.z + BF * sm.z * rc;
    o.w = AF * bh.w + BF * sm.w * rc;
    reinterpret_cast<float4*>(out)[(size_t)n * 32 + lane] = o;
}

extern "C" void kernel_launch(void* const* d_in, const int* in_sizes, int n_in,
                              void* d_out, int out_size, void* d_ws, size_t ws_size,
                              hipStream_t stream) {
    const float* base_x  = (const float*)d_in[0];
    const int*   bei     = (const int*)d_in[1];
    const float* bew     = (const float*)d_in[2];
    const float* local_x = (const float*)d_in[3];
    const int*   lai     = (const int*)d_in[4];
    const float* lav     = (const float*)d_in[5];
    const int*   c2o     = (const int*)d_in[6];
    const float* bW      = (const float*)d_in[7];
    const float* bb      = (const float*)d_in[8];
    const float* lW      = (const float*)d_in[9];
    const float* lb      = (const float*)d_in[10];
    const float* bgnw    = (const float*)d_in[11];
    const float* bgnb    = (const float*)d_in[12];
    const float* bgnms   = (const float*)d_in[13];
    const float* lgnw    = (const float*)d_in[14];
    const float* lgnb    = (const float*)d_in[15];
    const float* lgnms   = (const float*)d_in[16];

    const int N  = in_sizes[0] / 128;
    const int E  = in_sizes[2];
    const int M  = in_sizes[3] / 128;
    const int EL = in_sizes[5];

    float* ws = (float*)d_ws;
    size_t off = 0;
    float* deg     = ws + off; off += N;
    float* dinv    = ws + off; off += N;
    float* cntf    = ws + off; off += N;
    float* stats   = ws + off; off += 512;
    int* hcnt_b    = (int*)(ws + off); off += N;   // histogram, then re-zeroed as cursor
    int* rowptr_b  = (int*)(ws + off); off += N;
    int* hcnt_l    = (int*)(ws + off); off += M;
    int* rowptr_l  = (int*)(ws + off); off += M;
    int* bsum      = (int*)(ws + off); off += 128;
    int* boff      = (int*)(ws + off); off += 128;
    int* colv_b    = (int*)(ws + off); off += E;
    float* valv_b  = ws + off; off += E;
    int* colv_l    = (int*)(ws + off); off += EL;
    float* valv_l  = ws + off; off += EL;
    float* bx      = ws + off; off += (size_t)N * 128;  // later reused as summ
    float* agg     = ws + off; off += (size_t)N * 128;  // becomes base_h in place
    float* lx      = ws + off; off += (size_t)M * 128;
    float* lagg    = ws + off; off += (size_t)M * 128;
    float* summ    = bx;

    const int* brow = bei;
    const int* bcol = bei + E;
    const int* lrow = lai;
    const int* lcol = lai + EL;

    const int nb_b = (N + 1023) / 1024;
    const int nb_l = (M + 1023) / 1024;

    // ---- histograms + weighted degree ----
    hipMemsetAsync(deg, 0, (size_t)N * sizeof(float), stream);
    hipMemsetAsync(hcnt_b, 0, (size_t)N * sizeof(int), stream);
    hipMemsetAsync(hcnt_l, 0, (size_t)M * sizeof(int), stream);
    deg_hist_k<<<(E + 255) / 256, 256, 0, stream>>>(brow, bew, deg, hcnt_b, E);
    hist_k<<<(EL + 255) / 256, 256, 0, stream>>>(lrow, hcnt_l, EL);
    dinv_k<<<(N + 255) / 256, 256, 0, stream>>>(deg, dinv, N);

    // ---- build CSR rowptr (exclusive scan) + permute edges: base ----
    scan1_k<<<nb_b, 1024, 0, stream>>>(hcnt_b, rowptr_b, bsum, N);
    scan2_k<<<1, 128, 0, stream>>>(bsum, boff, nb_b);
    scan3_k<<<nb_b, 1024, 0, stream>>>(rowptr_b, boff, N);
    hipMemsetAsync(hcnt_b, 0, (size_t)N * sizeof(int), stream);  // reuse as cursor
    perm_b_k<<<(E + 255) / 256, 256, 0, stream>>>(brow, bcol, bew, dinv, rowptr_b,
                                                  hcnt_b, colv_b, valv_b, E);

    // ---- same for local ----
    scan1_k<<<nb_l, 1024, 0, stream>>>(hcnt_l, rowptr_l, bsum, M);
    scan2_k<<<1, 128, 0, stream>>>(bsum, boff, nb_l);
    scan3_k<<<nb_l, 1024, 0, stream>>>(rowptr_l, boff, M);
    hipMemsetAsync(hcnt_l, 0, (size_t)M * sizeof(int), stream);
    perm_l_k<<<(EL + 255) / 256, 256, 0, stream>>>(lrow, lcol, lav, rowptr_l,
                                                   hcnt_l, colv_l, valv_l, EL);

    // ---- base: GEMM -> CSR spmm (no atomics, no memset) -> graphnorm+relu ----
    gemm_xwt<<<(N + 63) / 64, 256, 0, stream>>>(base_x, bW, bb, bx, N);
    spmm_csr<<<(N * 64 + 255) / 256, 256, 0, stream>>>(rowptr_b, colv_b, valv_b, bx, agg, N, E);
    hipMemsetAsync(stats, 0, 256 * sizeof(float), stream);
    colstats<<<(N + 255) / 256, 256, 0, stream>>>(agg, stats, N);
    finalize_stats<<<1, 128, 0, stream>>>(stats, bgnw, bgnb, bgnms, (float)N);
    apply_relu<<<(N * 32 + 255) / 256, 256, 0, stream>>>(agg, stats + 256, N);

    // ---- local: GEMM -> CSR spmm -> stats ----
    gemm_xwt<<<(M + 63) / 64, 256, 0, stream>>>(local_x, lW, lb, lx, M);
    spmm_csr<<<(M * 64 + 255) / 256, 256, 0, stream>>>(rowptr_l, colv_l, valv_l, lx, lagg, M, EL);
    hipMemsetAsync(stats, 0, 256 * sizeof(float), stream);
    colstats<<<(M + 255) / 256, 256, 0, stream>>>(lagg, stats, M);
    finalize_stats<<<1, 128, 0, stream>>>(stats, lgnw, lgnb, lgnms, (float)M);

    // ---- mixing ----
    hipMemsetAsync(summ, 0, (size_t)N * 128 * sizeof(float), stream);
    hipMemsetAsync(cntf, 0, (size_t)N * sizeof(float), stream);
    float* out_base  = (float*)d_out;
    float* out_local = out_base + (size_t)N * 128;
    local_apply_mix<<<(M * 32 + 255) / 256, 256, 0, stream>>>(lagg, stats + 256, agg, c2o,
                                                              out_local, summ, cntf, M);
    base_mixed_k<<<(N * 32 + 255) / 256, 256, 0, stream>>>(agg, summ, cntf, out_base, N);
}

// Round 11
// 911.875 us; speedup vs baseline: 3.7091x; 1.1986x over previous
//
#include <hip/hip_runtime.h>

typedef __attribute__((ext_vector_type(8))) short bf16x8;
typedef __attribute__((ext_vector_type(4))) float f32x4;

#define AF 0.8f
#define BF (1.0f - 0.8f)
#define EPS 1e-5f

__device__ __forceinline__ ushort f2bf(float f) {
    union { float f; unsigned u; } v; v.f = f;
    unsigned u = v.u;
    return (ushort)((u + 0x7fffu + ((u >> 16) & 1u)) >> 16);
}

// ---------------- degree (weighted) + histogram (count) ----------------
__global__ void deg_hist_k(const int* __restrict__ rows, const float* __restrict__ w,
                           float* __restrict__ deg, int* __restrict__ hist, int E) {
    int e = blockIdx.x * 256 + threadIdx.x;
    if (e < E) {
        int r = rows[e];
        atomicAdd(&deg[r], w[e]);
        atomicAdd(&hist[r], 1);
    }
}

__global__ void hist_k(const int* __restrict__ rows, int* __restrict__ hist, int E) {
    int e = blockIdx.x * 256 + threadIdx.x;
    if (e < E) atomicAdd(&hist[rows[e]], 1);
}

__global__ void dinv_k(const float* __restrict__ deg, float* __restrict__ dinv, int n) {
    int i = blockIdx.x * 256 + threadIdx.x;
    if (i < n) {
        float d = deg[i];
        d = d < 0.5f ? d + 1.0f : d;
        dinv[i] = rsqrtf(d);
    }
}

// ---------------- exclusive scan (2-level, Hillis-Steele) ----------------
__global__ void scan1_k(const int* __restrict__ in, int* __restrict__ out,
                        int* __restrict__ bsum, int n) {
    __shared__ int sm[1024];
    int t = threadIdx.x;
    int i = blockIdx.x * 1024 + t;
    int v = (i < n) ? in[i] : 0;
    sm[t] = v;
    __syncthreads();
    for (int off = 1; off < 1024; off <<= 1) {
        int add = (t >= off) ? sm[t - off] : 0;
        __syncthreads();
        sm[t] += add;
        __syncthreads();
    }
    if (i < n) out[i] = sm[t] - v;  // exclusive
    if (t == 1023) bsum[blockIdx.x] = sm[1023];
}

__global__ void scan2_k(const int* __restrict__ bsum, int* __restrict__ boff, int n) {
    __shared__ int sm[128];
    int t = threadIdx.x;
    int v = (t < n) ? bsum[t] : 0;
    sm[t] = v;
    __syncthreads();
    for (int off = 1; off < 128; off <<= 1) {
        int add = (t >= off) ? sm[t - off] : 0;
        __syncthreads();
        sm[t] += add;
        __syncthreads();
    }
    if (t < n) boff[t] = sm[t] - v;  // exclusive
}

__global__ void scan3_k(int* __restrict__ out, const int* __restrict__ boff, int n) {
    int i = blockIdx.x * 1024 + threadIdx.x;
    if (i < n) out[i] += boff[blockIdx.x];
}

// ---------------- permute edges into row-sorted (CSR) order ----------------
__global__ void perm_b_k(const int* __restrict__ rows, const int* __restrict__ cols,
                         const float* __restrict__ w, const float* __restrict__ dinv,
                         const int* __restrict__ rowptr, int* __restrict__ cursor,
                         int* __restrict__ colv, float* __restrict__ valv, int E) {
    int e = blockIdx.x * 256 + threadIdx.x;
    if (e >= E) return;
    int r = rows[e], c = cols[e];
    int pos = rowptr[r] + atomicAdd(&cursor[r], 1);
    if (pos >= 0 && pos < E) {  // defensive: never scatter out of bounds
        colv[pos] = c;
        valv[pos] = dinv[r] * w[e] * dinv[c];
    }
}

__global__ void perm_l_k(const int* __restrict__ rows, const int* __restrict__ cols,
                         const float* __restrict__ w,
                         const int* __restrict__ rowptr, int* __restrict__ cursor,
                         int* __restrict__ colv, float* __restrict__ valv, int E) {
    int e = blockIdx.x * 256 + threadIdx.x;
    if (e >= E) return;
    int r = rows[e];
    int pos = rowptr[r] + atomicAdd(&cursor[r], 1);
    if (pos >= 0 && pos < E) {
        colv[pos] = cols[e];
        valv[pos] = w[e];
    }
}

__global__ void perm_c2o_k(const int* __restrict__ c2o, const int* __restrict__ rowptr,
                           int* __restrict__ cursor, int* __restrict__ member, int M) {
    int m = blockIdx.x * 256 + threadIdx.x;
    if (m >= M) return;
    int n = c2o[m];
    int pos = rowptr[n] + atomicAdd(&cursor[n], 1);
    if (pos >= 0 && pos < M) member[pos] = m;
}

// ---------------- CSR SpMM: one wave per row, no atomics ----------------
__global__ void spmm_csr(const int* __restrict__ rowptr, const int* __restrict__ colv,
                         const float* __restrict__ valv, const float* __restrict__ x,
                         float* __restrict__ out, int R, int Etot) {
    int wid = (blockIdx.x * 256 + threadIdx.x) >> 6;
    int lane = threadIdx.x & 63;
    if (wid >= R) return;
    int s = rowptr[wid];
    int eend = (wid == R - 1) ? Etot : rowptr[wid + 1];
    s = max(0, min(s, Etot));
    eend = max(s, min(eend, Etot));
    float2 acc0 = make_float2(0.f, 0.f);
    float2 acc1 = make_float2(0.f, 0.f);
    int i = s;
    for (; i + 1 < eend; i += 2) {
        int c0 = colv[i], c1 = colv[i + 1];
        float v0 = valv[i], v1 = valv[i + 1];
        float2 x0 = reinterpret_cast<const float2*>(x)[(size_t)c0 * 64 + lane];
        float2 x1 = reinterpret_cast<const float2*>(x)[(size_t)c1 * 64 + lane];
        acc0.x += v0 * x0.x; acc0.y += v0 * x0.y;
        acc1.x += v1 * x1.x; acc1.y += v1 * x1.y;
    }
    if (i < eend) {
        int c = colv[i];
        float v = valv[i];
        float2 xv = reinterpret_cast<const float2*>(x)[(size_t)c * 64 + lane];
        acc0.x += v * xv.x; acc0.y += v * xv.y;
    }
    acc0.x += acc1.x; acc0.y += acc1.y;
    reinterpret_cast<float2*>(out)[(size_t)wid * 64 + lane] = acc0;
}

// ---------------- GEMM: out[r][c] = sum_k X[r][k]*W[c][k] + bias[c] -------------
__global__ __launch_bounds__(256) void gemm_xwt(const float* __restrict__ X,
                                                const float* __restrict__ W,
                                                const float* __restrict__ bias,
                                                float* __restrict__ out, int R) {
    __shared__ ushort Wl[128 * 136];
    __shared__ ushort Xl[64 * 136];
    int t = threadIdx.x;
    int row0 = blockIdx.x * 64;

    for (int i = 0; i < 16; i++) {
        int vid = t + i * 256;
        int idx = vid * 4;
        int r = idx >> 7, c = idx & 127;
        float4 v = reinterpret_cast<const float4*>(W)[vid];
        ushort4 b;
        b.x = f2bf(v.x); b.y = f2bf(v.y); b.z = f2bf(v.z); b.w = f2bf(v.w);
        *reinterpret_cast<ushort4*>(&Wl[r * 136 + c]) = b;
    }
    for (int i = 0; i < 8; i++) {
        int vid = t + i * 256;
        int idx = vid * 4;
        int r = idx >> 7, c = idx & 127;
        int gr = row0 + r;
        float4 v = make_float4(0.f, 0.f, 0.f, 0.f);
        if (gr < R) v = reinterpret_cast<const float4*>(X)[(size_t)gr * 32 + (c >> 2)];
        ushort4 b;
        b.x = f2bf(v.x); b.y = f2bf(v.y); b.z = f2bf(v.z); b.w = f2bf(v.w);
        *reinterpret_cast<ushort4*>(&Xl[r * 136 + c]) = b;
    }
    __syncthreads();

    int w = t >> 6, l = t & 63;
    int lr = l & 15, lg = l >> 4;

    f32x4 acc[8] = {};
#pragma unroll
    for (int kk = 0; kk < 4; kk++) {
        bf16x8 a = *reinterpret_cast<const bf16x8*>(&Xl[(w * 16 + lr) * 136 + kk * 32 + lg * 8]);
#pragma unroll
        for (int j = 0; j < 8; j++) {
            bf16x8 b = *reinterpret_cast<const bf16x8*>(&Wl[(j * 16 + lr) * 136 + kk * 32 + lg * 8]);
            acc[j] = __builtin_amdgcn_mfma_f32_16x16x32_bf16(a, b, acc[j], 0, 0, 0);
        }
    }
#pragma unroll
    for (int j = 0; j < 8; j++) {
        int c = j * 16 + lr;
        float bi = bias[c];
#pragma unroll
        for (int i = 0; i < 4; i++) {
            int r = row0 + w * 16 + lg * 4 + i;
            if (r < R) out[(size_t)r * 128 + c] = acc[j][i] + bi;
        }
    }
}

// ---------------- column stats ----------------
__global__ void colstats(const float* __restrict__ x, float* __restrict__ sums, int R) {
    int t = threadIdx.x;
    int g = t & 31, rb = t >> 5;
    int r0 = blockIdx.x * 256;
    int rend = min(r0 + 256, R);
    float4 s = make_float4(0.f, 0.f, 0.f, 0.f);
    float4 q = make_float4(0.f, 0.f, 0.f, 0.f);
    for (int r = r0 + rb; r < rend; r += 8) {
        float4 v = reinterpret_cast<const float4*>(x)[(size_t)r * 32 + g];
        s.x += v.x; s.y += v.y; s.z += v.z; s.w += v.w;
        q.x += v.x * v.x; q.y += v.y * v.y; q.z += v.z * v.z; q.w += v.w * v.w;
    }
    s.x += __shfl_xor(s.x, 32); s.y += __shfl_xor(s.y, 32);
    s.z += __shfl_xor(s.z, 32); s.w += __shfl_xor(s.w, 32);
    q.x += __shfl_xor(q.x, 32); q.y += __shfl_xor(q.y, 32);
    q.z += __shfl_xor(q.z, 32); q.w += __shfl_xor(q.w, 32);
    if ((t & 32) == 0) {
        int c = g * 4;
        atomicAdd(&sums[c + 0], s.x); atomicAdd(&sums[c + 1], s.y);
        atomicAdd(&sums[c + 2], s.z); atomicAdd(&sums[c + 3], s.w);
        atomicAdd(&sums[128 + c + 0], q.x); atomicAdd(&sums[128 + c + 1], q.y);
        atomicAdd(&sums[128 + c + 2], q.z); atomicAdd(&sums[128 + c + 3], q.w);
    }
}

__global__ void finalize_stats(float* __restrict__ stats, const float* __restrict__ wgt,
                               const float* __restrict__ bias, const float* __restrict__ msc,
                               float R) {
    int j = threadIdx.x;
    float mean = stats[j] / R;
    float ex2 = stats[128 + j] / R;
    float ms = msc[j];
    float d = ms * mean;
    float var = ex2 - 2.0f * d * mean + d * d;
    float rstd = rsqrtf(var + EPS);
    float sc = wgt[j] * rstd;
    stats[256 + j] = sc;
    stats[384 + j] = bias[j] - sc * d;
}

__global__ void apply_relu(float* __restrict__ x, const float* __restrict__ ss, int R) {
    __shared__ float lss[256];
    int t = threadIdx.x;
    lss[t] = ss[t];
    __syncthreads();
    int idx = blockIdx.x * 256 + t;
    if (idx >= R * 32) return;
    int c = (idx & 31) * 4;
    float4 v = reinterpret_cast<float4*>(x)[idx];
    v.x = fmaxf(lss[c + 0] * v.x + lss[128 + c + 0], 0.f);
    v.y = fmaxf(lss[c + 1] * v.y + lss[128 + c + 1], 0.f);
    v.z = fmaxf(lss[c + 2] * v.z + lss[128 + c + 2], 0.f);
    v.w = fmaxf(lss[c + 3] * v.w + lss[128 + c + 3], 0.f);
    reinterpret_cast<float4*>(x)[idx] = v;
}

// out_local[m] = a*relu(lscale*lagg+lshift) + (1-a)*base_h[c2o[m]]  (no atomics)
__global__ void local_apply_k(const float* __restrict__ lagg, const float* __restrict__ ss,
                              const float* __restrict__ base_h, const int* __restrict__ c2o,
                              float* __restrict__ out_local, int M) {
    __shared__ float lss[256];
    int t = threadIdx.x;
    lss[t] = ss[t];
    __syncthreads();
    int gid = blockIdx.x * 256 + t;
    int m = gid >> 5, lane = gid & 31;
    if (m >= M) return;
    int n = c2o[m];
    float4 lv = reinterpret_cast<const float4*>(lagg)[(size_t)m * 32 + lane];
    float4 bv = reinterpret_cast<const float4*>(base_h)[(size_t)n * 32 + lane];
    int c = lane * 4;
    float4 o;
    o.x = AF * fmaxf(lss[c + 0] * lv.x + lss[128 + c + 0], 0.f) + BF * bv.x;
    o.y = AF * fmaxf(lss[c + 1] * lv.y + lss[128 + c + 1], 0.f) + BF * bv.y;
    o.z = AF * fmaxf(lss[c + 2] * lv.z + lss[128 + c + 2], 0.f) + BF * bv.z;
    o.w = AF * fmaxf(lss[c + 3] * lv.w + lss[128 + c + 3], 0.f) + BF * bv.w;
    reinterpret_cast<float4*>(out_local)[(size_t)m * 32 + lane] = o;
}

// base_mixed: one wave per base node, gather member rows of out_local
__global__ void base_mixed_gather(const float* __restrict__ base_h,
                                  const float* __restrict__ out_local,
                                  const int* __restrict__ rowptr,
                                  const int* __restrict__ member,
                                  float* __restrict__ out, int N_, int Mtot) {
    int wid = (blockIdx.x * 256 + threadIdx.x) >> 6;
    int lane = threadIdx.x & 63;
    if (wid >= N_) return;
    int s = rowptr[wid];
    int eend = (wid == N_ - 1) ? Mtot : rowptr[wid + 1];
    s = max(0, min(s, Mtot));
    eend = max(s, min(eend, Mtot));
    float2 acc = make_float2(0.f, 0.f);
    for (int i = s; i < eend; i++) {
        int m = member[i];
        float2 v = reinterpret_cast<const float2*>(out_local)[(size_t)m * 64 + lane];
        acc.x += v.x; acc.y += v.y;
    }
    float rc = 1.0f / fmaxf((float)(eend - s), 1.0f);
    float2 bh = reinterpret_cast<const float2*>(base_h)[(size_t)wid * 64 + lane];
    float2 o;
    o.x = AF * bh.x + BF * acc.x * rc;
    o.y = AF * bh.y + BF * acc.y * rc;
    reinterpret_cast<float2*>(out)[(size_t)wid * 64 + lane] = o;
}

extern "C" void kernel_launch(void* const* d_in, const int* in_sizes, int n_in,
                              void* d_out, int out_size, void* d_ws, size_t ws_size,
                              hipStream_t stream) {
    const float* base_x  = (const float*)d_in[0];
    const int*   bei     = (const int*)d_in[1];
    const float* bew     = (const float*)d_in[2];
    const float* local_x = (const float*)d_in[3];
    const int*   lai     = (const int*)d_in[4];
    const float* lav     = (const float*)d_in[5];
    const int*   c2o     = (const int*)d_in[6];
    const float* bW      = (const float*)d_in[7];
    const float* bb      = (const float*)d_in[8];
    const float* lW      = (const float*)d_in[9];
    const float* lb      = (const float*)d_in[10];
    const float* bgnw    = (const float*)d_in[11];
    const float* bgnb    = (const float*)d_in[12];
    const float* bgnms   = (const float*)d_in[13];
    const float* lgnw    = (const float*)d_in[14];
    const float* lgnb    = (const float*)d_in[15];
    const float* lgnms   = (const float*)d_in[16];

    const int N  = in_sizes[0] / 128;
    const int E  = in_sizes[2];
    const int M  = in_sizes[3] / 128;
    const int EL = in_sizes[5];

    // ---- workspace layout (~92 MB; no aliasing/reuse) ----
    float* ws = (float*)d_ws;
    size_t off = 0;
    float* deg     = ws + off; off += N;
    float* dinv    = ws + off; off += N;
    float* stats   = ws + off; off += 512;
    int* hcnt_b    = (int*)(ws + off); off += N;
    int* rowptr_b  = (int*)(ws + off); off += N;
    int* hcnt_l    = (int*)(ws + off); off += M;
    int* rowptr_l  = (int*)(ws + off); off += M;
    int* hcnt_n    = (int*)(ws + off); off += N;
    int* rowptr_n  = (int*)(ws + off); off += N;
    int* bsum      = (int*)(ws + off); off += 128;
    int* boff      = (int*)(ws + off); off += 128;
    int* member    = (int*)(ws + off); off += M;
    int* colv_b    = (int*)(ws + off); off += E;
    float* valv_b  = ws + off; off += E;
    int* colv_l    = (int*)(ws + off); off += EL;
    float* valv_l  = ws + off; off += EL;
    float* agg     = ws + off; off += (size_t)N * 128;  // becomes base_h in place
    float* lagg    = ws + off; off += (size_t)M * 128;

    // GEMM outputs staged inside d_out (dead by the time out_* is written):
    float* out_base  = (float*)d_out;
    float* out_local = out_base + (size_t)N * 128;
    float* bx = out_base;    // read only by base spmm_csr; out_base written last
    float* lx = out_local;   // read only by local spmm_csr; out_local written later

    const int* brow = bei;
    const int* bcol = bei + E;
    const int* lrow = lai;
    const int* lcol = lai + EL;

    const int nb_b = (N + 1023) / 1024;
    const int nb_l = (M + 1023) / 1024;

    // ---- histograms + weighted degree ----
    hipMemsetAsync(deg, 0, (size_t)N * sizeof(float), stream);
    hipMemsetAsync(hcnt_b, 0, (size_t)N * sizeof(int), stream);
    hipMemsetAsync(hcnt_l, 0, (size_t)M * sizeof(int), stream);
    hipMemsetAsync(hcnt_n, 0, (size_t)N * sizeof(int), stream);
    deg_hist_k<<<(E + 255) / 256, 256, 0, stream>>>(brow, bew, deg, hcnt_b, E);
    hist_k<<<(EL + 255) / 256, 256, 0, stream>>>(lrow, hcnt_l, EL);
    hist_k<<<(M + 255) / 256, 256, 0, stream>>>(c2o, hcnt_n, M);
    dinv_k<<<(N + 255) / 256, 256, 0, stream>>>(deg, dinv, N);

    // ---- base CSR ----
    scan1_k<<<nb_b, 1024, 0, stream>>>(hcnt_b, rowptr_b, bsum, N);
    scan2_k<<<1, 128, 0, stream>>>(bsum, boff, nb_b);
    scan3_k<<<nb_b, 1024, 0, stream>>>(rowptr_b, boff, N);
    hipMemsetAsync(hcnt_b, 0, (size_t)N * sizeof(int), stream);
    perm_b_k<<<(E + 255) / 256, 256, 0, stream>>>(brow, bcol, bew, dinv, rowptr_b,
                                                  hcnt_b, colv_b, valv_b, E);

    // ---- local CSR ----
    scan1_k<<<nb_l, 1024, 0, stream>>>(hcnt_l, rowptr_l, bsum, M);
    scan2_k<<<1, 128, 0, stream>>>(bsum, boff, nb_l);
    scan3_k<<<nb_l, 1024, 0, stream>>>(rowptr_l, boff, M);
    hipMemsetAsync(hcnt_l, 0, (size_t)M * sizeof(int), stream);
    perm_l_k<<<(EL + 255) / 256, 256, 0, stream>>>(lrow, lcol, lav, rowptr_l,
                                                   hcnt_l, colv_l, valv_l, EL);

    // ---- c2o CSR (members per base node) ----
    scan1_k<<<nb_b, 1024, 0, stream>>>(hcnt_n, rowptr_n, bsum, N);
    scan2_k<<<1, 128, 0, stream>>>(bsum, boff, nb_b);
    scan3_k<<<nb_b, 1024, 0, stream>>>(rowptr_n, boff, N);
    hipMemsetAsync(hcnt_n, 0, (size_t)N * sizeof(int), stream);
    perm_c2o_k<<<(M + 255) / 256, 256, 0, stream>>>(c2o, rowptr_n, hcnt_n, member, M);

    // ---- base: GEMM -> CSR spmm -> graphnorm+relu ----
    gemm_xwt<<<(N + 63) / 64, 256, 0, stream>>>(base_x, bW, bb, bx, N);
    spmm_csr<<<(N * 64 + 255) / 256, 256, 0, stream>>>(rowptr_b, colv_b, valv_b, bx, agg, N, E);
    hipMemsetAsync(stats, 0, 256 * sizeof(float), stream);
    colstats<<<(N + 255) / 256, 256, 0, stream>>>(agg, stats, N);
    finalize_stats<<<1, 128, 0, stream>>>(stats, bgnw, bgnb, bgnms, (float)N);
    apply_relu<<<(N * 32 + 255) / 256, 256, 0, stream>>>(agg, stats + 256, N);

    // ---- local: GEMM -> CSR spmm -> stats ----
    gemm_xwt<<<(M + 63) / 64, 256, 0, stream>>>(local_x, lW, lb, lx, M);
    spmm_csr<<<(M * 64 + 255) / 256, 256, 0, stream>>>(rowptr_l, colv_l, valv_l, lx, lagg, M, EL);
    hipMemsetAsync(stats, 0, 256 * sizeof(float), stream);
    colstats<<<(M + 255) / 256, 256, 0, stream>>>(lagg, stats, M);
    finalize_stats<<<1, 128, 0, stream>>>(stats, lgnw, lgnb, lgnms, (float)M);

    // ---- mixing (atomic-free); overwrites the staged lx/bx regions ----
    local_apply_k<<<(M * 32 + 255) / 256, 256, 0, stream>>>(lagg, stats + 256, agg, c2o,
                                                            out_local, M);
    base_mixed_gather<<<(N * 64 + 255) / 256, 256, 0, stream>>>(agg, out_local, rowptr_n,
                                                                member, out_base, N, M);
}

// Round 13
// 727.326 us; speedup vs baseline: 4.6503x; 1.2537x over previous
//
#include <hip/hip_runtime.h>

typedef __attribute__((ext_vector_type(8))) short bf16x8;
typedef __attribute__((ext_vector_type(4))) float f32x4;

#define AF 0.8f
#define BF (1.0f - 0.8f)
#define EPS 1e-5f
#define CS_NB 1024  // colstats phase-1 grid

__device__ __forceinline__ ushort f2bf(float f) {
    union { float f; unsigned u; } v; v.f = f;
    unsigned u = v.u;
    return (ushort)((u + 0x7fffu + ((u >> 16) & 1u)) >> 16);
}

// ---------------- degree (weighted) + histogram (count) ----------------
__global__ void deg_hist_k(const int* __restrict__ rows, const float* __restrict__ w,
                           float* __restrict__ deg, int* __restrict__ hist, int E) {
    int e = blockIdx.x * 256 + threadIdx.x;
    if (e < E) {
        int r = rows[e];
        atomicAdd(&deg[r], w[e]);
        atomicAdd(&hist[r], 1);
    }
}

__global__ void hist_k(const int* __restrict__ rows, int* __restrict__ hist, int E) {
    int e = blockIdx.x * 256 + threadIdx.x;
    if (e < E) atomicAdd(&hist[rows[e]], 1);
}

__global__ void dinv_k(const float* __restrict__ deg, float* __restrict__ dinv, int n) {
    int i = blockIdx.x * 256 + threadIdx.x;
    if (i < n) {
        float d = deg[i];
        d = d < 0.5f ? d + 1.0f : d;
        dinv[i] = rsqrtf(d);
    }
}

// ---------------- exclusive scan (2-level, Hillis-Steele) ----------------
__global__ void scan1_k(const int* __restrict__ in, int* __restrict__ out,
                        int* __restrict__ bsum, int n) {
    __shared__ int sm[1024];
    int t = threadIdx.x;
    int i = blockIdx.x * 1024 + t;
    int v = (i < n) ? in[i] : 0;
    sm[t] = v;
    __syncthreads();
    for (int off = 1; off < 1024; off <<= 1) {
        int add = (t >= off) ? sm[t - off] : 0;
        __syncthreads();
        sm[t] += add;
        __syncthreads();
    }
    if (i < n) out[i] = sm[t] - v;  // exclusive
    if (t == 1023) bsum[blockIdx.x] = sm[1023];
}

__global__ void scan2_k(const int* __restrict__ bsum, int* __restrict__ boff, int n) {
    __shared__ int sm[128];
    int t = threadIdx.x;
    int v = (t < n) ? bsum[t] : 0;
    sm[t] = v;
    __syncthreads();
    for (int off = 1; off < 128; off <<= 1) {
        int add = (t >= off) ? sm[t - off] : 0;
        __syncthreads();
        sm[t] += add;
        __syncthreads();
    }
    if (t < n) boff[t] = sm[t] - v;  // exclusive
}

__global__ void scan3_k(int* __restrict__ out, const int* __restrict__ boff, int n) {
    int i = blockIdx.x * 1024 + threadIdx.x;
    if (i < n) out[i] += boff[blockIdx.x];
}

// ---------------- permute edges into row-sorted (CSR) order ----------------
__global__ void perm_b_k(const int* __restrict__ rows, const int* __restrict__ cols,
                         const float* __restrict__ w, const float* __restrict__ dinv,
                         const int* __restrict__ rowptr, int* __restrict__ cursor,
                         int* __restrict__ colv, float* __restrict__ valv, int E) {
    int e = blockIdx.x * 256 + threadIdx.x;
    if (e >= E) return;
    int r = rows[e], c = cols[e];
    int pos = rowptr[r] + atomicAdd(&cursor[r], 1);
    if (pos >= 0 && pos < E) {  // defensive: never scatter out of bounds
        colv[pos] = c;
        valv[pos] = dinv[r] * w[e] * dinv[c];
    }
}

__global__ void perm_l_k(const int* __restrict__ rows, const int* __restrict__ cols,
                         const float* __restrict__ w,
                         const int* __restrict__ rowptr, int* __restrict__ cursor,
                         int* __restrict__ colv, float* __restrict__ valv, int E) {
    int e = blockIdx.x * 256 + threadIdx.x;
    if (e >= E) return;
    int r = rows[e];
    int pos = rowptr[r] + atomicAdd(&cursor[r], 1);
    if (pos >= 0 && pos < E) {
        colv[pos] = cols[e];
        valv[pos] = w[e];
    }
}

__global__ void perm_c2o_k(const int* __restrict__ c2o, const int* __restrict__ rowptr,
                           int* __restrict__ cursor, int* __restrict__ member, int M) {
    int m = blockIdx.x * 256 + threadIdx.x;
    if (m >= M) return;
    int n = c2o[m];
    int pos = rowptr[n] + atomicAdd(&cursor[n], 1);
    if (pos >= 0 && pos < M) member[pos] = m;
}

// ---------------- CSR SpMM: one wave per row, no atomics ----------------
__global__ void spmm_csr(const int* __restrict__ rowptr, const int* __restrict__ colv,
                         const float* __restrict__ valv, const float* __restrict__ x,
                         float* __restrict__ out, int R, int Etot) {
    int wid = (blockIdx.x * 256 + threadIdx.x) >> 6;
    int lane = threadIdx.x & 63;
    if (wid >= R) return;
    int s = rowptr[wid];
    int eend = (wid == R - 1) ? Etot : rowptr[wid + 1];
    s = max(0, min(s, Etot));
    eend = max(s, min(eend, Etot));
    float2 acc0 = make_float2(0.f, 0.f);
    float2 acc1 = make_float2(0.f, 0.f);
    int i = s;
    for (; i + 1 < eend; i += 2) {
        int c0 = colv[i], c1 = colv[i + 1];
        float v0 = valv[i], v1 = valv[i + 1];
        float2 x0 = reinterpret_cast<const float2*>(x)[(size_t)c0 * 64 + lane];
        float2 x1 = reinterpret_cast<const float2*>(x)[(size_t)c1 * 64 + lane];
        acc0.x += v0 * x0.x; acc0.y += v0 * x0.y;
        acc1.x += v1 * x1.x; acc1.y += v1 * x1.y;
    }
    if (i < eend) {
        int c = colv[i];
        float v = valv[i];
        float2 xv = reinterpret_cast<const float2*>(x)[(size_t)c * 64 + lane];
        acc0.x += v * xv.x; acc0.y += v * xv.y;
    }
    acc0.x += acc1.x; acc0.y += acc1.y;
    reinterpret_cast<float2*>(out)[(size_t)wid * 64 + lane] = acc0;
}

// ---------------- GEMM: out[r][c] = sum_k X[r][k]*W[c][k] + bias[c] -------------
__global__ __launch_bounds__(256) void gemm_xwt(const float* __restrict__ X,
                                                const float* __restrict__ W,
                                                const float* __restrict__ bias,
                                                float* __restrict__ out, int R) {
    __shared__ ushort Wl[128 * 136];
    __shared__ ushort Xl[64 * 136];
    int t = threadIdx.x;
    int row0 = blockIdx.x * 64;

    for (int i = 0; i < 16; i++) {
        int vid = t + i * 256;
        int idx = vid * 4;
        int r = idx >> 7, c = idx & 127;
        float4 v = reinterpret_cast<const float4*>(W)[vid];
        ushort4 b;
        b.x = f2bf(v.x); b.y = f2bf(v.y); b.z = f2bf(v.z); b.w = f2bf(v.w);
        *reinterpret_cast<ushort4*>(&Wl[r * 136 + c]) = b;
    }
    for (int i = 0; i < 8; i++) {
        int vid = t + i * 256;
        int idx = vid * 4;
        int r = idx >> 7, c = idx & 127;
        int gr = row0 + r;
        float4 v = make_float4(0.f, 0.f, 0.f, 0.f);
        if (gr < R) v = reinterpret_cast<const float4*>(X)[(size_t)gr * 32 + (c >> 2)];
        ushort4 b;
        b.x = f2bf(v.x); b.y = f2bf(v.y); b.z = f2bf(v.z); b.w = f2bf(v.w);
        *reinterpret_cast<ushort4*>(&Xl[r * 136 + c]) = b;
    }
    __syncthreads();

    int w = t >> 6, l = t & 63;
    int lr = l & 15, lg = l >> 4;

    f32x4 acc[8] = {};
#pragma unroll
    for (int kk = 0; kk < 4; kk++) {
        bf16x8 a = *reinterpret_cast<const bf16x8*>(&Xl[(w * 16 + lr) * 136 + kk * 32 + lg * 8]);
#pragma unroll
        for (int j = 0; j < 8; j++) {
            bf16x8 b = *reinterpret_cast<const bf16x8*>(&Wl[(j * 16 + lr) * 136 + kk * 32 + lg * 8]);
            acc[j] = __builtin_amdgcn_mfma_f32_16x16x32_bf16(a, b, acc[j], 0, 0, 0);
        }
    }
#pragma unroll
    for (int j = 0; j < 8; j++) {
        int c = j * 16 + lr;
        float bi = bias[c];
#pragma unroll
        for (int i = 0; i < 4; i++) {
            int r = row0 + w * 16 + lg * 4 + i;
            if (r < R) out[(size_t)r * 128 + c] = acc[j][i] + bi;
        }
    }
}

// ---------------- column stats: 2-phase, no atomics ----------------
// Phase 1: CS_NB grid-stride blocks -> per-block partials [256] (sum|sumsq)
__global__ __launch_bounds__(256) void colstats_p1(const float* __restrict__ x,
                                                   float* __restrict__ partials, int R) {
    int t = threadIdx.x;
    int g = t & 31, rb = t >> 5;
    float4 s = make_float4(0.f, 0.f, 0.f, 0.f);
    float4 q = make_float4(0.f, 0.f, 0.f, 0.f);
    for (int r = blockIdx.x * 8 + rb; r < R; r += CS_NB * 8) {
        float4 v = reinterpret_cast<const float4*>(x)[(size_t)r * 32 + g];
        s.x += v.x; s.y += v.y; s.z += v.z; s.w += v.w;
        q.x += v.x * v.x; q.y += v.y * v.y; q.z += v.z * v.z; q.w += v.w * v.w;
    }
    __shared__ float4 smS[8][32];
    __shared__ float4 smQ[8][32];
    smS[rb][g] = s;
    smQ[rb][g] = q;
    __syncthreads();
    if (t < 32) {
        float4 S = smS[0][t], Q = smQ[0][t];
#pragma unroll
        for (int i = 1; i < 8; i++) {
            float4 a = smS[i][t], b = smQ[i][t];
            S.x += a.x; S.y += a.y; S.z += a.z; S.w += a.w;
            Q.x += b.x; Q.y += b.y; Q.z += b.z; Q.w += b.w;
        }
        int c = t * 4;
        float* p = partials + (size_t)blockIdx.x * 256;
        p[c + 0] = S.x; p[c + 1] = S.y; p[c + 2] = S.z; p[c + 3] = S.w;
        p[128 + c + 0] = Q.x; p[128 + c + 1] = Q.y; p[128 + c + 2] = Q.z; p[128 + c + 3] = Q.w;
    }
}

// Phase 2: reduce partials + finalize scale/shift (stats[256..384)=scale, [384..512)=shift)
__global__ void colstats_p2(const float* __restrict__ partials, const float* __restrict__ wgt,
                            const float* __restrict__ bias, const float* __restrict__ msc,
                            float* __restrict__ stats, float Rf) {
    int t = threadIdx.x;
    float acc = 0.f;
    for (int b = 0; b < CS_NB; b++) acc += partials[(size_t)b * 256 + t];
    __shared__ float lds[256];
    lds[t] = acc;
    __syncthreads();
    if (t < 128) {
        float mean = lds[t] / Rf;
        float ex2 = lds[128 + t] / Rf;
        float ms = msc[t];
        float d = ms * mean;
        float var = ex2 - 2.0f * d * mean + d * d;
        float sc = wgt[t] * rsqrtf(var + EPS);
        stats[256 + t] = sc;
        stats[384 + t] = bias[t] - sc * d;
    }
}

__global__ void apply_relu(float* __restrict__ x, const float* __restrict__ ss, int R) {
    __shared__ float lss[256];
    int t = threadIdx.x;
    lss[t] = ss[t];
    __syncthreads();
    int idx = blockIdx.x * 256 + t;
    if (idx >= R * 32) return;
    int c = (idx & 31) * 4;
    float4 v = reinterpret_cast<float4*>(x)[idx];
    v.x = fmaxf(lss[c + 0] * v.x + lss[128 + c + 0], 0.f);
    v.y = fmaxf(lss[c + 1] * v.y + lss[128 + c + 1], 0.f);
    v.z = fmaxf(lss[c + 2] * v.z + lss[128 + c + 2], 0.f);
    v.w = fmaxf(lss[c + 3] * v.w + lss[128 + c + 3], 0.f);
    reinterpret_cast<float4*>(x)[idx] = v;
}

// out_local[m] = a*relu(lscale*lagg+lshift) + (1-a)*base_h[c2o[m]]  (no atomics)
__global__ void local_apply_k(const float* __restrict__ lagg, const float* __restrict__ ss,
                              const float* __restrict__ base_h, const int* __restrict__ c2o,
                              float* __restrict__ out_local, int M) {
    __shared__ float lss[256];
    int t = threadIdx.x;
    lss[t] = ss[t];
    __syncthreads();
    int gid = blockIdx.x * 256 + t;
    int m = gid >> 5, lane = gid & 31;
    if (m >= M) return;
    int n = c2o[m];
    float4 lv = reinterpret_cast<const float4*>(lagg)[(size_t)m * 32 + lane];
    float4 bv = reinterpret_cast<const float4*>(base_h)[(size_t)n * 32 + lane];
    int c = lane * 4;
    float4 o;
    o.x = AF * fmaxf(lss[c + 0] * lv.x + lss[128 + c + 0], 0.f) + BF * bv.x;
    o.y = AF * fmaxf(lss[c + 1] * lv.y + lss[128 + c + 1], 0.f) + BF * bv.y;
    o.z = AF * fmaxf(lss[c + 2] * lv.z + lss[128 + c + 2], 0.f) + BF * bv.z;
    o.w = AF * fmaxf(lss[c + 3] * lv.w + lss[128 + c + 3], 0.f) + BF * bv.w;
    reinterpret_cast<float4*>(out_local)[(size_t)m * 32 + lane] = o;
}

// base_mixed: one wave per base node, gather member rows of out_local
__global__ void base_mixed_gather(const float* __restrict__ base_h,
                                  const float* __restrict__ out_local,
                                  const int* __restrict__ rowptr,
                                  const int* __restrict__ member,
                                  float* __restrict__ out, int N_, int Mtot) {
    int wid = (blockIdx.x * 256 + threadIdx.x) >> 6;
    int lane = threadIdx.x & 63;
    if (wid >= N_) return;
    int s = rowptr[wid];
    int eend = (wid == N_ - 1) ? Mtot : rowptr[wid + 1];
    s = max(0, min(s, Mtot));
    eend = max(s, min(eend, Mtot));
    float2 acc = make_float2(0.f, 0.f);
    for (int i = s; i < eend; i++) {
        int m = member[i];
        float2 v = reinterpret_cast<const float2*>(out_local)[(size_t)m * 64 + lane];
        acc.x += v.x; acc.y += v.y;
    }
    float rc = 1.0f / fmaxf((float)(eend - s), 1.0f);
    float2 bh = reinterpret_cast<const float2*>(base_h)[(size_t)wid * 64 + lane];
    float2 o;
    o.x = AF * bh.x + BF * acc.x * rc;
    o.y = AF * bh.y + BF * acc.y * rc;
    reinterpret_cast<float2*>(out)[(size_t)wid * 64 + lane] = o;
}

extern "C" void kernel_launch(void* const* d_in, const int* in_sizes, int n_in,
                              void* d_out, int out_size, void* d_ws, size_t ws_size,
                              hipStream_t stream) {
    const float* base_x  = (const float*)d_in[0];
    const int*   bei     = (const int*)d_in[1];
    const float* bew     = (const float*)d_in[2];
    const float* local_x = (const float*)d_in[3];
    const int*   lai     = (const int*)d_in[4];
    const float* lav     = (const float*)d_in[5];
    const int*   c2o     = (const int*)d_in[6];
    const float* bW      = (const float*)d_in[7];
    const float* bb      = (const float*)d_in[8];
    const float* lW      = (const float*)d_in[9];
    const float* lb      = (const float*)d_in[10];
    const float* bgnw    = (const float*)d_in[11];
    const float* bgnb    = (const float*)d_in[12];
    const float* bgnms   = (const float*)d_in[13];
    const float* lgnw    = (const float*)d_in[14];
    const float* lgnb    = (const float*)d_in[15];
    const float* lgnms   = (const float*)d_in[16];

    const int N  = in_sizes[0] / 128;
    const int E  = in_sizes[2];
    const int M  = in_sizes[3] / 128;
    const int EL = in_sizes[5];

    // ---- workspace layout (~94 MB; no aliasing/reuse) ----
    float* ws = (float*)d_ws;
    size_t off = 0;
    float* deg     = ws + off; off += N;
    float* dinv    = ws + off; off += N;
    float* stats   = ws + off; off += 512;
    float* partials= ws + off; off += (size_t)CS_NB * 256;
    int* hcnt_b    = (int*)(ws + off); off += N;
    int* rowptr_b  = (int*)(ws + off); off += N;
    int* hcnt_l    = (int*)(ws + off); off += M;
    int* rowptr_l  = (int*)(ws + off); off += M;
    int* hcnt_n    = (int*)(ws + off); off += N;
    int* rowptr_n  = (int*)(ws + off); off += N;
    int* bsum      = (int*)(ws + off); off += 128;
    int* boff      = (int*)(ws + off); off += 128;
    int* member    = (int*)(ws + off); off += M;
    int* colv_b    = (int*)(ws + off); off += E;
    float* valv_b  = ws + off; off += E;
    int* colv_l    = (int*)(ws + off); off += EL;
    float* valv_l  = ws + off; off += EL;
    float* agg     = ws + off; off += (size_t)N * 128;  // becomes base_h in place
    float* lagg    = ws + off; off += (size_t)M * 128;

    // GEMM outputs staged inside d_out (dead by the time out_* is written):
    float* out_base  = (float*)d_out;
    float* out_local = out_base + (size_t)N * 128;
    float* bx = out_base;    // read only by base spmm_csr; out_base written last
    float* lx = out_local;   // read only by local spmm_csr; out_local written later

    const int* brow = bei;
    const int* bcol = bei + E;
    const int* lrow = lai;
    const int* lcol = lai + EL;

    const int nb_b = (N + 1023) / 1024;
    const int nb_l = (M + 1023) / 1024;

    // ---- histograms + weighted degree ----
    hipMemsetAsync(deg, 0, (size_t)N * sizeof(float), stream);
    hipMemsetAsync(hcnt_b, 0, (size_t)N * sizeof(int), stream);
    hipMemsetAsync(hcnt_l, 0, (size_t)M * sizeof(int), stream);
    hipMemsetAsync(hcnt_n, 0, (size_t)N * sizeof(int), stream);
    deg_hist_k<<<(E + 255) / 256, 256, 0, stream>>>(brow, bew, deg, hcnt_b, E);
    hist_k<<<(EL + 255) / 256, 256, 0, stream>>>(lrow, hcnt_l, EL);
    hist_k<<<(M + 255) / 256, 256, 0, stream>>>(c2o, hcnt_n, M);
    dinv_k<<<(N + 255) / 256, 256, 0, stream>>>(deg, dinv, N);

    // ---- base CSR ----
    scan1_k<<<nb_b, 1024, 0, stream>>>(hcnt_b, rowptr_b, bsum, N);
    scan2_k<<<1, 128, 0, stream>>>(bsum, boff, nb_b);
    scan3_k<<<nb_b, 1024, 0, stream>>>(rowptr_b, boff, N);
    hipMemsetAsync(hcnt_b, 0, (size_t)N * sizeof(int), stream);
    perm_b_k<<<(E + 255) / 256, 256, 0, stream>>>(brow, bcol, bew, dinv, rowptr_b,
                                                  hcnt_b, colv_b, valv_b, E);

    // ---- local CSR ----
    scan1_k<<<nb_l, 1024, 0, stream>>>(hcnt_l, rowptr_l, bsum, M);
    scan2_k<<<1, 128, 0, stream>>>(bsum, boff, nb_l);
    scan3_k<<<nb_l, 1024, 0, stream>>>(rowptr_l, boff, M);
    hipMemsetAsync(hcnt_l, 0, (size_t)M * sizeof(int), stream);
    perm_l_k<<<(EL + 255) / 256, 256, 0, stream>>>(lrow, lcol, lav, rowptr_l,
                                                   hcnt_l, colv_l, valv_l, EL);

    // ---- c2o CSR (members per base node) ----
    scan1_k<<<nb_b, 1024, 0, stream>>>(hcnt_n, rowptr_n, bsum, N);
    scan2_k<<<1, 128, 0, stream>>>(bsum, boff, nb_b);
    scan3_k<<<nb_b, 1024, 0, stream>>>(rowptr_n, boff, N);
    hipMemsetAsync(hcnt_n, 0, (size_t)N * sizeof(int), stream);
    perm_c2o_k<<<(M + 255) / 256, 256, 0, stream>>>(c2o, rowptr_n, hcnt_n, member, M);

    // ---- base: GEMM -> CSR spmm -> graphnorm+relu ----
    gemm_xwt<<<(N + 63) / 64, 256, 0, stream>>>(base_x, bW, bb, bx, N);
    spmm_csr<<<(N * 64 + 255) / 256, 256, 0, stream>>>(rowptr_b, colv_b, valv_b, bx, agg, N, E);
    colstats_p1<<<CS_NB, 256, 0, stream>>>(agg, partials, N);
    colstats_p2<<<1, 256, 0, stream>>>(partials, bgnw, bgnb, bgnms, stats, (float)N);
    apply_relu<<<(N * 32 + 255) / 256, 256, 0, stream>>>(agg, stats + 256, N);

    // ---- local: GEMM -> CSR spmm -> stats ----
    gemm_xwt<<<(M + 63) / 64, 256, 0, stream>>>(local_x, lW, lb, lx, M);
    spmm_csr<<<(M * 64 + 255) / 256, 256, 0, stream>>>(rowptr_l, colv_l, valv_l, lx, lagg, M, EL);
    colstats_p1<<<CS_NB, 256, 0, stream>>>(lagg, partials, M);
    colstats_p2<<<1, 256, 0, stream>>>(partials, lgnw, lgnb, lgnms, stats, (float)M);

    // ---- mixing (atomic-free); overwrites the staged lx/bx regions ----
    local_apply_k<<<(M * 32 + 255) / 256, 256, 0, stream>>>(lagg, stats + 256, agg, c2o,
                                                            out_local, M);
    base_mixed_gather<<<(N * 64 + 255) / 256, 256, 0, stream>>>(agg, out_local, rowptr_n,
                                                                member, out_base, N, M);
}